// Round 1
// baseline (904.869 us; speedup 1.0000x reference)
//
#include <hip/hip_runtime.h>
#include <hip/hip_bf16.h>

// out[b,o] = sum_k x[b,k] * W[o,k] + bias[o]
// x: (1048576, 128) fp32, W: (128, 128) fp32 row-major (o,k), b: (128,1) fp32
//
// v2: persistent blocks + pipelined prefetch + swapped-operand MFMA.
//  - 512 blocks (2/CU), each owns 16 consecutive 128-row tiles; W staged to LDS
//    ONCE per block (was 8192x), x loads for tile t+1 issued before tile t's MFMA
//    so HBM reads stay in flight across the whole block lifetime.
//  - MFMA operands swapped: D = W * x^T, so D[row=out-col][col=batch-row].
//    Each lane then holds 4 CONSECUTIVE out columns per nt-tile -> float4 stores
//    (16 dwordx4 per wave-tile instead of 64 scalar dwords), and bias becomes
//    the accumulator init (float4 per nt).
// Memory floor: 1.07 GB HBM traffic -> ~170 us at 6.3 TB/s achievable.

typedef __attribute__((ext_vector_type(8))) short bf16x8;   // 8 bf16 = 4 VGPRs
typedef __attribute__((ext_vector_type(4))) float f32x4;    // MFMA C/D

#define LDSW 136             // 128 + 8 bf16 pad: row stride 272B -> 2-way bank aliasing (free)
#define TILES_PER_BLOCK 16
#define NBLOCKS 512          // 2 blocks/CU on 256 CUs

__device__ __forceinline__ short f2bf(float f) {
    union { __hip_bfloat16 h; short s; } u;
    u.h = __float2bfloat16(f);
    return u.s;
}

__global__ __launch_bounds__(256, 2)
void linear_mfma_kernel(const float* __restrict__ x,
                        const float* __restrict__ W,
                        const float* __restrict__ bias,
                        float* __restrict__ out)
{
    __shared__ short sW[128 * LDSW];   // bf16 bits, row-major (o, k), padded

    const int tid  = threadIdx.x;
    const int lane = tid & 63;
    const int wave = tid >> 6;
    const int lr   = lane & 15;   // within-tile index (A.m / B.n / C.col)
    const int lq   = lane >> 4;   // quad index

    // ---- Stage W (128x128 fp32) -> LDS bf16, ONCE per persistent block.
    #pragma unroll
    for (int it = 0; it < 16; ++it) {
        const int i  = tid + it * 256;     // float4 index
        const int n  = i >> 5;             // 32 float4 per 128-elem row
        const int k4 = (i & 31) << 2;
        const float4 w = ((const float4*)W)[i];
        short4 p;
        p.x = f2bf(w.x); p.y = f2bf(w.y); p.z = f2bf(w.z); p.w = f2bf(w.w);
        *(short4*)&sW[n * LDSW + k4] = p;  // 8B-aligned (272*n + 2*k4)
    }

    // ---- Bias as acc-init fragments: bv[nt] = bias[nt*16 + lq*4 .. +3]
    f32x4 bv[8];
    #pragma unroll
    for (int nt = 0; nt < 8; ++nt)
        bv[nt] = ((const f32x4*)bias)[nt * 4 + lq];

    __syncthreads();   // sW ready (only barrier in the kernel)

    const long tile0 = (long)blockIdx.x * TILES_PER_BLOCK;

    // ---- x prefetch buffer: one 32x128 fp32 wave-tile = 16 float4/lane (64 VGPR)
    float4 xl[16];
    {
        const long row0 = tile0 * 128 + wave * 32;
        #pragma unroll
        for (int mt = 0; mt < 2; ++mt) {
            const float* xr = x + (row0 + mt * 16 + lr) * 128 + lq * 8;
            #pragma unroll
            for (int ks = 0; ks < 4; ++ks) {
                xl[mt * 8 + ks * 2]     = *(const float4*)(xr + ks * 32);
                xl[mt * 8 + ks * 2 + 1] = *(const float4*)(xr + ks * 32 + 4);
            }
        }
    }

    #pragma unroll 1
    for (int t = 0; t < TILES_PER_BLOCK; ++t) {
        const long row0 = (tile0 + t) * 128 + wave * 32;

        // -- convert current tile fp32 -> bf16 fragments (waits on xl loads)
        //    B-operand layout: x[row = lr][k = lq*8 + j]
        bf16x8 af[2][4];
        #pragma unroll
        for (int mt = 0; mt < 2; ++mt)
            #pragma unroll
            for (int ks = 0; ks < 4; ++ks) {
                const float4 f0 = xl[mt * 8 + ks * 2];
                const float4 f1 = xl[mt * 8 + ks * 2 + 1];
                bf16x8 a;
                a[0] = f2bf(f0.x); a[1] = f2bf(f0.y); a[2] = f2bf(f0.z); a[3] = f2bf(f0.w);
                a[4] = f2bf(f1.x); a[5] = f2bf(f1.y); a[6] = f2bf(f1.z); a[7] = f2bf(f1.w);
                af[mt][ks] = a;
            }

        // -- issue next tile's loads NOW so they fly under MFMA + stores
        if (t + 1 < TILES_PER_BLOCK) {
            const long nrow0 = (tile0 + t + 1) * 128 + wave * 32;
            #pragma unroll
            for (int mt = 0; mt < 2; ++mt) {
                const float* xr = x + (nrow0 + mt * 16 + lr) * 128 + lq * 8;
                #pragma unroll
                for (int ks = 0; ks < 4; ++ks) {
                    xl[mt * 8 + ks * 2]     = *(const float4*)(xr + ks * 32);
                    xl[mt * 8 + ks * 2 + 1] = *(const float4*)(xr + ks * 32 + 4);
                }
            }
        }

        // -- acc init = bias (out = W.x^T + b)
        f32x4 acc[2][8];
        #pragma unroll
        for (int mt = 0; mt < 2; ++mt)
            #pragma unroll
            for (int nt = 0; nt < 8; ++nt)
                acc[mt][nt] = bv[nt];

        // -- MFMA: A = W-frag (LDS), B = x-frag. D[row = out-col][col = batch-row]
        //    A layout: W[o = nt*16 + lr][k = ks*32 + lq*8 + j]  (same LDS read as v1)
        #pragma unroll
        for (int ks = 0; ks < 4; ++ks) {
            #pragma unroll
            for (int nt = 0; nt < 8; ++nt) {
                const bf16x8 wfrag =
                    *(const bf16x8*)&sW[(nt * 16 + lr) * LDSW + ks * 32 + lq * 8];
                acc[0][nt] = __builtin_amdgcn_mfma_f32_16x16x32_bf16(
                    wfrag, af[0][ks], acc[0][nt], 0, 0, 0);
                acc[1][nt] = __builtin_amdgcn_mfma_f32_16x16x32_bf16(
                    wfrag, af[1][ks], acc[1][nt], 0, 0, 0);
            }
        }

        // -- Epilogue: lane holds out[row0 + mt*16 + lr][nt*16 + lq*4 .. +3]
        //    -> contiguous float4 per lane, 1KB per wave-store instruction.
        #pragma unroll
        for (int mt = 0; mt < 2; ++mt) {
            float* orow = out + (row0 + mt * 16 + lr) * 128 + lq * 4;
            #pragma unroll
            for (int nt = 0; nt < 8; ++nt)
                *(f32x4*)(orow + nt * 16) = acc[mt][nt];
        }
    }
}

extern "C" void kernel_launch(void* const* d_in, const int* in_sizes, int n_in,
                              void* d_out, int out_size, void* d_ws, size_t ws_size,
                              hipStream_t stream) {
    const float* x = (const float*)d_in[0];   // (1048576, 128)
    const float* W = (const float*)d_in[1];   // (128, 128)
    const float* b = (const float*)d_in[2];   // (128, 1)
    float* out = (float*)d_out;               // (1048576, 128)

    dim3 grid(NBLOCKS);    // 512 persistent blocks, 16 row-tiles each
    dim3 block(256);
    linear_mfma_kernel<<<grid, block, 0, stream>>>(x, W, b, out);
}

// Round 2
// 892.349 us; speedup vs baseline: 1.0140x; 1.0140x over previous
//
#include <hip/hip_runtime.h>
#include <hip/hip_bf16.h>

// out[b,o] = sum_k x[b,k] * W[o,k] + bias[o]
// x: (1048576, 128) fp32, W: (128, 128) fp32 row-major (o,k), b: (128,1) fp32
//
// v3: one-shot grid (v1 structure — inter-block overlap is the pipeline) +
//     swapped-operand MFMA (v2's good half) + occupancy 2->4 blocks/CU.
//  - 8192 blocks, one 128x128 output tile each. Scheduler backfill overlaps
//    block N's stores with block N+1's loads (this is what v2's persistence
//    destroyed: +32us).
//  - MFMA: A = W-frag (LDS), B = x-frag => D[row=out-col][col=batch-row].
//    Lane holds 4 CONSECUTIVE out columns -> float4 stores (16 dwordx4 per
//    wave-tile vs 64 scalar dwords in v1).
//  - bias via LDS at epilogue (transient regs); __launch_bounds__(256,4)
//    caps at 128 VGPR -> 4 blocks/CU (LDS 35.3KB/block, 4 fit in 160KB).
//  - nontemporal x loads / out stores: streamed exactly once, keep L2 for W.
// Memory floor: 1.07 GB HBM traffic -> ~170 us at 6.3 TB/s achievable.

typedef __attribute__((ext_vector_type(8))) short bf16x8;   // 8 bf16 = 4 VGPRs
typedef __attribute__((ext_vector_type(4))) float f32x4;    // MFMA C/D, 16B ld/st

#define LDSW 136   // 128 + 8 bf16 pad: row stride 272B -> 2-way bank aliasing (free)

__device__ __forceinline__ short f2bf(float f) {
    union { __hip_bfloat16 h; short s; } u;
    u.h = __float2bfloat16(f);
    return u.s;
}

__global__ __launch_bounds__(256, 4)
void linear_mfma_kernel(const float* __restrict__ x,
                        const float* __restrict__ W,
                        const float* __restrict__ bias,
                        float* __restrict__ out)
{
    __shared__ short sW[128 * LDSW];   // bf16 bits, row-major (o, k), padded
    __shared__ float sB[128];          // bias

    const int tid  = threadIdx.x;
    const int lane = tid & 63;
    const int wave = tid >> 6;
    const int lr   = lane & 15;   // within-tile index
    const int lq   = lane >> 4;   // quad index

    // ---- Stage W (128x128 fp32) -> LDS bf16. 4096 float4 chunks / 256 thr = 16 each.
    //      W is L2-resident across all 8192 blocks: plain (cached) loads.
    #pragma unroll
    for (int it = 0; it < 16; ++it) {
        const int i  = tid + it * 256;     // float4 index
        const int n  = i >> 5;             // 32 float4 per 128-elem row
        const int k4 = (i & 31) << 2;
        const float4 w = ((const float4*)W)[i];
        short4 p;
        p.x = f2bf(w.x); p.y = f2bf(w.y); p.z = f2bf(w.z); p.w = f2bf(w.w);
        *(short4*)&sW[n * LDSW + k4] = p;  // 8B-aligned (272*n + 2*k4)
    }
    if (tid < 128) sB[tid] = bias[tid];

    // ---- x B-fragments direct from global (fp32 -> bf16 in-register).
    //      B layout: x[row = lr][k = lq*8 + j]; nontemporal (read exactly once).
    const long row0 = (long)blockIdx.x * 128 + wave * 32;
    bf16x8 af[2][4];
    #pragma unroll
    for (int mt = 0; mt < 2; ++mt) {
        const float* xr = x + (row0 + mt * 16 + lr) * 128 + lq * 8;
        #pragma unroll
        for (int ks = 0; ks < 4; ++ks) {
            const f32x4 f0 = __builtin_nontemporal_load((const f32x4*)(xr + ks * 32));
            const f32x4 f1 = __builtin_nontemporal_load((const f32x4*)(xr + ks * 32 + 4));
            bf16x8 a;
            a[0] = f2bf(f0[0]); a[1] = f2bf(f0[1]); a[2] = f2bf(f0[2]); a[3] = f2bf(f0[3]);
            a[4] = f2bf(f1[0]); a[5] = f2bf(f1[1]); a[6] = f2bf(f1[2]); a[7] = f2bf(f1[3]);
            af[mt][ks] = a;
        }
    }

    __syncthreads();   // sW/sB ready

    f32x4 acc[2][8];
    #pragma unroll
    for (int mt = 0; mt < 2; ++mt)
        #pragma unroll
        for (int nt = 0; nt < 8; ++nt)
            acc[mt][nt] = (f32x4){0.f, 0.f, 0.f, 0.f};

    // ---- MFMA: A = W-frag (LDS), B = x-frag. D[row = out-col][col = batch-row]
    //      A layout: W[o = nt*16 + lr][k = ks*32 + lq*8 + j]
    #pragma unroll
    for (int ks = 0; ks < 4; ++ks) {
        #pragma unroll
        for (int nt = 0; nt < 8; ++nt) {
            const bf16x8 wfrag =
                *(const bf16x8*)&sW[(nt * 16 + lr) * LDSW + ks * 32 + lq * 8];
            acc[0][nt] = __builtin_amdgcn_mfma_f32_16x16x32_bf16(
                wfrag, af[0][ks], acc[0][nt], 0, 0, 0);
            acc[1][nt] = __builtin_amdgcn_mfma_f32_16x16x32_bf16(
                wfrag, af[1][ks], acc[1][nt], 0, 0, 0);
        }
    }

    // ---- Epilogue: lane holds out[row0 + mt*16 + lr][nt*16 + lq*4 .. +3]
    //      -> contiguous float4 per lane; bias frag from LDS (transient).
    #pragma unroll
    for (int mt = 0; mt < 2; ++mt) {
        float* orow = out + (row0 + mt * 16 + lr) * 128 + lq * 4;
        #pragma unroll
        for (int nt = 0; nt < 8; ++nt) {
            const f32x4 bv = *(const f32x4*)&sB[nt * 16 + lq * 4];
            const f32x4 v = acc[mt][nt] + bv;
            __builtin_nontemporal_store(v, (f32x4*)(orow + nt * 16));
        }
    }
}

extern "C" void kernel_launch(void* const* d_in, const int* in_sizes, int n_in,
                              void* d_out, int out_size, void* d_ws, size_t ws_size,
                              hipStream_t stream) {
    const float* x = (const float*)d_in[0];   // (1048576, 128)
    const float* W = (const float*)d_in[1];   // (128, 128)
    const float* b = (const float*)d_in[2];   // (128, 1)
    float* out = (float*)d_out;               // (1048576, 128)

    const int BATCH = 1048576;
    dim3 grid(BATCH / 128);   // 8192 one-shot blocks, 128x128 tile each
    dim3 block(256);
    linear_mfma_kernel<<<grid, block, 0, stream>>>(x, W, b, out);
}

// Round 3
// 882.057 us; speedup vs baseline: 1.0259x; 1.0117x over previous
//
#include <hip/hip_runtime.h>
#include <hip/hip_bf16.h>

// out[b,o] = sum_k x[b,k] * W[o,k] + bias[o]
// x: (1048576, 128) fp32, W: (128, 128) fp32 row-major (o,k), b: (128,1) fp32
//
// v4 = v1 structure (one-shot 8192-block grid, launch_bounds(256,2), plain
//      cached loads — every deviation from this regressed) with EXACTLY ONE
//      change vs v1: swapped-operand MFMA enabling a float4 epilogue.
//  - MFMA: A = W-frag (LDS), B = x-frag => D[row = out-col][col = batch-row].
//    Lane holds 4 CONSECUTIVE out columns per nt-tile -> 16 dwordx4 stores
//    per lane instead of 64 scalar dwords (4x fewer store issue slots).
//  - bias folded into accumulator init (no epilogue VALU adds).
//  - x HBM loads issued before W staging loads (W is L2-hit; start the
//    bottleneck stream first).
//  - NO launch_bounds(256,4) [v3: -19.5us, VGPR cap killed load MLP],
//    NO persistence [v2: -32us], NO nontemporal hints [unproven suspect].
// Memory floor: 1.073 GB HBM traffic -> ~171 us at 6.29 TB/s measured ceiling.

typedef __attribute__((ext_vector_type(8))) short bf16x8;   // 8 bf16 = 4 VGPRs
typedef __attribute__((ext_vector_type(4))) float f32x4;    // MFMA C/D, 16B ld/st

#define LDSW 136   // 128 + 8 bf16 pad: row stride 272B -> 2-way bank aliasing (free)

__device__ __forceinline__ short f2bf(float f) {
    union { __hip_bfloat16 h; short s; } u;
    u.h = __float2bfloat16(f);
    return u.s;
}

__global__ __launch_bounds__(256, 2)
void linear_mfma_kernel(const float* __restrict__ x,
                        const float* __restrict__ W,
                        const float* __restrict__ bias,
                        float* __restrict__ out)
{
    __shared__ short sW[128 * LDSW];   // bf16 bits, row-major (o, k), padded

    const int tid  = threadIdx.x;
    const int lane = tid & 63;
    const int wave = tid >> 6;
    const int lr   = lane & 15;   // within-tile index
    const int lq   = lane >> 4;   // quad index

    const long row0 = (long)blockIdx.x * 128 + wave * 32;

    // ---- Issue the x HBM loads FIRST (bottleneck stream; 16 float4 in flight).
    f32x4 xl[16];
    #pragma unroll
    for (int mt = 0; mt < 2; ++mt) {
        const float* xr = x + (row0 + mt * 16 + lr) * 128 + lq * 8;
        #pragma unroll
        for (int ks = 0; ks < 4; ++ks) {
            xl[mt * 8 + ks * 2]     = *(const f32x4*)(xr + ks * 32);
            xl[mt * 8 + ks * 2 + 1] = *(const f32x4*)(xr + ks * 32 + 4);
        }
    }

    // ---- Stage W (128x128 fp32, L2-resident) -> LDS bf16. 16 float4/thread.
    #pragma unroll
    for (int it = 0; it < 16; ++it) {
        const int i  = tid + it * 256;     // float4 index
        const int n  = i >> 5;             // 32 float4 per 128-elem row
        const int k4 = (i & 31) << 2;
        const float4 w = ((const float4*)W)[i];
        short4 p;
        p.x = f2bf(w.x); p.y = f2bf(w.y); p.z = f2bf(w.z); p.w = f2bf(w.w);
        *(short4*)&sW[n * LDSW + k4] = p;  // 8B-aligned (272*n + 2*k4)
    }

    // ---- Bias as acc-init fragments: bv[nt][r] = bias[nt*16 + lq*4 + r]
    f32x4 bv[8];
    #pragma unroll
    for (int nt = 0; nt < 8; ++nt)
        bv[nt] = ((const f32x4*)bias)[nt * 4 + lq];

    // ---- Convert x fp32 -> bf16 B-fragments: x[row = lr][k = lq*8 + j]
    bf16x8 af[2][4];
    #pragma unroll
    for (int mt = 0; mt < 2; ++mt)
        #pragma unroll
        for (int ks = 0; ks < 4; ++ks) {
            const f32x4 f0 = xl[mt * 8 + ks * 2];
            const f32x4 f1 = xl[mt * 8 + ks * 2 + 1];
            bf16x8 a;
            a[0] = f2bf(f0[0]); a[1] = f2bf(f0[1]); a[2] = f2bf(f0[2]); a[3] = f2bf(f0[3]);
            a[4] = f2bf(f1[0]); a[5] = f2bf(f1[1]); a[6] = f2bf(f1[2]); a[7] = f2bf(f1[3]);
            af[mt][ks] = a;
        }

    __syncthreads();   // sW ready

    // ---- acc init = bias (out = W.x^T + b)
    f32x4 acc[2][8];
    #pragma unroll
    for (int mt = 0; mt < 2; ++mt)
        #pragma unroll
        for (int nt = 0; nt < 8; ++nt)
            acc[mt][nt] = bv[nt];

    // ---- MFMA: A = W-frag (LDS), B = x-frag. D[row = out-col][col = batch-row]
    //      A layout: W[o = nt*16 + lr][k = ks*32 + lq*8 + j]
    #pragma unroll
    for (int ks = 0; ks < 4; ++ks) {
        #pragma unroll
        for (int nt = 0; nt < 8; ++nt) {
            const bf16x8 wfrag =
                *(const bf16x8*)&sW[(nt * 16 + lr) * LDSW + ks * 32 + lq * 8];
            acc[0][nt] = __builtin_amdgcn_mfma_f32_16x16x32_bf16(
                wfrag, af[0][ks], acc[0][nt], 0, 0, 0);
            acc[1][nt] = __builtin_amdgcn_mfma_f32_16x16x32_bf16(
                wfrag, af[1][ks], acc[1][nt], 0, 0, 0);
        }
    }

    // ---- Epilogue: lane stores out[row0 + mt*16 + lr][nt*16 + lq*4 .. +3]
    //      16 contiguous-16B stores per lane, bias already in acc.
    #pragma unroll
    for (int mt = 0; mt < 2; ++mt) {
        float* orow = out + (row0 + mt * 16 + lr) * 128 + lq * 4;
        #pragma unroll
        for (int nt = 0; nt < 8; ++nt)
            *(f32x4*)(orow + nt * 16) = acc[mt][nt];
    }
}

extern "C" void kernel_launch(void* const* d_in, const int* in_sizes, int n_in,
                              void* d_out, int out_size, void* d_ws, size_t ws_size,
                              hipStream_t stream) {
    const float* x = (const float*)d_in[0];   // (1048576, 128)
    const float* W = (const float*)d_in[1];   // (128, 128)
    const float* b = (const float*)d_in[2];   // (128, 1)
    float* out = (float*)d_out;               // (1048576, 128)

    const int BATCH = 1048576;
    dim3 grid(BATCH / 128);   // 8192 one-shot blocks, 128x128 tile each
    dim3 block(256);
    linear_mfma_kernel<<<grid, block, 0, stream>>>(x, W, b, out);
}

// Round 4
// 845.091 us; speedup vs baseline: 1.0707x; 1.0437x over previous
//
#include <hip/hip_runtime.h>
#include <hip/hip_bf16.h>

// out[b,o] = sum_k x[b,k] * W[o,k] + bias[o]
// x: (1048576, 128) fp32, W: (128, 128) fp32 row-major (o,k), b: (128,1) fp32
//
// v5: double wave concurrency, keep everything else that won.
//  - 512-thread blocks, 8 waves, each wave owns 16 rows (per-wave tile halved
//    vs v1). Natural VGPR ~110 -> launch_bounds(512,4) cap (128) is NOT
//    binding (v3's mistake: 64-reg load burst under a 128 cap). 2 blocks/CU
//    -> 16 waves/CU (was 8): deeper load queue, decorrelated wave phases.
//  - Same aggregate W staging as v1 (one 64KB stage per 128 output rows).
//  - v1 phase order (W stage first, x loads converted INLINE — let the
//    compiler pick pipeline depth; v4's materialized xl[16] regressed).
//  - Swapped-operand MFMA: D[row=out-col][col=batch-row] -> float4 stores;
//    bias added at epilogue from LDS (transient regs, nothing pinned).
// Memory floor: 1.073 GB HBM traffic -> ~171 us at 6.29 TB/s measured ceiling.

typedef __attribute__((ext_vector_type(8))) short bf16x8;   // 8 bf16 = 4 VGPRs
typedef __attribute__((ext_vector_type(4))) float f32x4;    // MFMA C/D, 16B ld/st

#define LDSW 136   // 128 + 8 bf16 pad: row stride 272B -> 2-way bank aliasing (free)

__device__ __forceinline__ short f2bf(float f) {
    union { __hip_bfloat16 h; short s; } u;
    u.h = __float2bfloat16(f);
    return u.s;
}

__global__ __launch_bounds__(512, 4)
void linear_mfma_kernel(const float* __restrict__ x,
                        const float* __restrict__ W,
                        const float* __restrict__ bias,
                        float* __restrict__ out)
{
    __shared__ short sW[128 * LDSW];   // bf16 bits, row-major (o, k), padded
    __shared__ float sB[128];          // bias

    const int tid  = threadIdx.x;
    const int lane = tid & 63;
    const int wave = tid >> 6;        // 0..7
    const int lr   = lane & 15;       // within-tile index
    const int lq   = lane >> 4;       // quad index

    // ---- Stage W (128x128 fp32, L2-resident) -> LDS bf16. 8 float4/thread.
    #pragma unroll
    for (int it = 0; it < 8; ++it) {
        const int i  = tid + it * 512;     // float4 index (4096 total)
        const int n  = i >> 5;             // 32 float4 per 128-elem row
        const int k4 = (i & 31) << 2;
        const float4 w = ((const float4*)W)[i];
        short4 p;
        p.x = f2bf(w.x); p.y = f2bf(w.y); p.z = f2bf(w.z); p.w = f2bf(w.w);
        *(short4*)&sW[n * LDSW + k4] = p;  // 8B-aligned (272*n + 2*k4)
    }
    if (tid < 128) sB[tid] = bias[tid];

    // ---- x B-fragments, loaded + converted INLINE (compiler-pipelined).
    //      Wave owns rows [row0, row0+16). B layout: x[b = lr][k = lq*8 + j].
    const long row0 = (long)blockIdx.x * 128 + wave * 16;
    const float* xr = x + (row0 + lr) * 128 + lq * 8;
    bf16x8 af[4];
    #pragma unroll
    for (int ks = 0; ks < 4; ++ks) {
        const f32x4 f0 = *(const f32x4*)(xr + ks * 32);
        const f32x4 f1 = *(const f32x4*)(xr + ks * 32 + 4);
        bf16x8 a;
        a[0] = f2bf(f0[0]); a[1] = f2bf(f0[1]); a[2] = f2bf(f0[2]); a[3] = f2bf(f0[3]);
        a[4] = f2bf(f1[0]); a[5] = f2bf(f1[1]); a[6] = f2bf(f1[2]); a[7] = f2bf(f1[3]);
        af[ks] = a;
    }

    __syncthreads();   // sW/sB ready

    f32x4 acc[8];
    #pragma unroll
    for (int nt = 0; nt < 8; ++nt)
        acc[nt] = (f32x4){0.f, 0.f, 0.f, 0.f};

    // ---- MFMA: A = W-frag (LDS), B = x-frag. D[row = out-col][col = batch-row]
    //      A layout: W[o = nt*16 + lr][k = ks*32 + lq*8 + j]. 32 MFMA/wave.
    #pragma unroll
    for (int ks = 0; ks < 4; ++ks) {
        #pragma unroll
        for (int nt = 0; nt < 8; ++nt) {
            const bf16x8 wfrag =
                *(const bf16x8*)&sW[(nt * 16 + lr) * LDSW + ks * 32 + lq * 8];
            acc[nt] = __builtin_amdgcn_mfma_f32_16x16x32_bf16(
                wfrag, af[ks], acc[nt], 0, 0, 0);
        }
    }

    // ---- Epilogue: lane holds out[row0 + lr][nt*16 + lq*4 .. +3]
    //      -> contiguous float4 per lane; bias frag from LDS (transient).
    float* orow = out + (row0 + lr) * 128 + lq * 4;
    #pragma unroll
    for (int nt = 0; nt < 8; ++nt) {
        const f32x4 bv = *(const f32x4*)&sB[nt * 16 + lq * 4];
        *(f32x4*)(orow + nt * 16) = acc[nt] + bv;
    }
}

extern "C" void kernel_launch(void* const* d_in, const int* in_sizes, int n_in,
                              void* d_out, int out_size, void* d_ws, size_t ws_size,
                              hipStream_t stream) {
    const float* x = (const float*)d_in[0];   // (1048576, 128)
    const float* W = (const float*)d_in[1];   // (128, 128)
    const float* b = (const float*)d_in[2];   // (128, 1)
    float* out = (float*)d_out;               // (1048576, 128)

    const int BATCH = 1048576;
    dim3 grid(BATCH / 128);   // 8192 blocks x 512 threads; 128 rows per block
    dim3 block(512);
    linear_mfma_kernel<<<grid, block, 0, stream>>>(x, W, b, out);
}